// Round 8
// baseline (1566.017 us; speedup 1.0000x reference)
//
#include <hip/hip_runtime.h>
#include <hip/hip_bf16.h>

#define NN 32768
#define EE 262144
#define FD 128
#define NL 64
#define MROW 16     // nodes per block — 2048 blocks, 8/CU, 32 waves/CU
#define SROW 132    // LDS row stride (ushorts)

typedef short v8s __attribute__((ext_vector_type(8)));
typedef float v4f __attribute__((ext_vector_type(4)));

__device__ __forceinline__ unsigned short f2bf(float x) {
    unsigned u = __builtin_bit_cast(unsigned, x);
    u += 0x7fffu + ((u >> 16) & 1u);
    return (unsigned short)(u >> 16);
}
__device__ __forceinline__ float bf2f(unsigned short h) {
    unsigned u = ((unsigned)h) << 16;
    return __builtin_bit_cast(float, u);
}
// accumulate 8 bf16 (packed in v8s) into acc[8]
__device__ __forceinline__ void acc8_bf16(float* acc, v8s r) {
    const int* d = (const int*)&r;
#pragma unroll
    for (int k = 0; k < 4; k++) {
        unsigned u = (unsigned)d[k];
        acc[2 * k]     += __builtin_bit_cast(float, u << 16);
        acc[2 * k + 1] += __builtin_bit_cast(float, u & 0xffff0000u);
    }
}

// ---------- setup ----------
__global__ __launch_bounds__(256) void k_deg(const int* __restrict__ dst,
                                             int* __restrict__ cnt) {
    int e = blockIdx.x * 256 + threadIdx.x;
    if (e < EE) atomicAdd(&cnt[dst[e]], 1);
}

// degree histogram (64 bins, clamp)
__global__ __launch_bounds__(256) void k_hist(const int* __restrict__ cnt,
                                              int* __restrict__ hist) {
    int i = blockIdx.x * 256 + threadIdx.x;
    int d = cnt[i];
    atomicAdd(&hist[d > 63 ? 63 : d], 1);
}
// exclusive scan of the 64 bins (one wave)
__global__ __launch_bounds__(64) void k_binscan(const int* __restrict__ hist,
                                                int* __restrict__ hoff) {
    int t = threadIdx.x;
    int v = hist[t];
    int x = v;
#pragma unroll
    for (int off = 1; off < 64; off <<= 1) {
        int y = __shfl_up(x, off);
        if (t >= off) x += y;
    }
    hoff[t] = x - v;
}
// scatter: node i -> sorted slot p; record perm both ways + sorted degree
__global__ __launch_bounds__(256) void k_scatter(const int* __restrict__ cnt,
                                                 const int* __restrict__ hoff,
                                                 int* __restrict__ hcur,
                                                 int* __restrict__ sortid,
                                                 int* __restrict__ inv,
                                                 int* __restrict__ cntS) {
    int i = blockIdx.x * 256 + threadIdx.x;
    int d = cnt[i];
    int b = d > 63 ? 63 : d;
    int r = atomicAdd(&hcur[b], 1);
    int p = hoff[b] + r;
    sortid[p] = i;
    inv[i] = p;
    cntS[p] = d;
}

// hierarchical scan (over PERMUTED degrees cntS)
__global__ __launch_bounds__(256) void k_scanA(const int* __restrict__ cnt,
                                               int* __restrict__ bsum) {
    __shared__ int ws[4];
    int tid = threadIdx.x;
    int v = cnt[blockIdx.x * 256 + tid];
    int x = v;
#pragma unroll
    for (int off = 1; off < 64; off <<= 1) x += __shfl_xor(x, off);
    if ((tid & 63) == 0) ws[tid >> 6] = x;
    __syncthreads();
    if (tid == 0) bsum[blockIdx.x] = ws[0] + ws[1] + ws[2] + ws[3];
}
__global__ __launch_bounds__(128) void k_scanB(const int* __restrict__ bsum,
                                               int* __restrict__ boff,
                                               int* __restrict__ offs) {
    __shared__ int s0;
    int tid = threadIdx.x;
    int v = bsum[tid];
    int lane = tid & 63, w = tid >> 6;
    int x = v;
#pragma unroll
    for (int off = 1; off < 64; off <<= 1) {
        int y = __shfl_up(x, off);
        if (lane >= off) x += y;
    }
    if (tid == 63) s0 = x;
    __syncthreads();
    int excl = x - v + (w ? s0 : 0);
    boff[tid] = excl;
    if (tid == 127) offs[NN] = excl + v;
}
// scanC + dinv (permuted space: dinv[p] belongs to node sortid[p])
__global__ __launch_bounds__(256) void k_scanC(const int* __restrict__ cnt,
                                               const int* __restrict__ boff,
                                               int* __restrict__ offs,
                                               float* __restrict__ dinv) {
    __shared__ int ws[4];
    int tid = threadIdx.x;
    int i = blockIdx.x * 256 + tid;
    int v = cnt[i];
    int lane = tid & 63, w = tid >> 6;
    int x = v;
#pragma unroll
    for (int off = 1; off < 64; off <<= 1) {
        int y = __shfl_up(x, off);
        if (lane >= off) x += y;
    }
    if (lane == 63) ws[w] = x;
    __syncthreads();
    int wexcl = 0;
#pragma unroll
    for (int k = 0; k < 4; k++) if (k < w) wexcl += ws[k];
    offs[i] = boff[blockIdx.x] + wexcl + x - v;
    dinv[i] = rsqrtf((float)v + 1.0f);
}

// merged fill + wcast + xcast (all in permuted space)
__global__ __launch_bounds__(256) void k_prep(const int* __restrict__ src,
                                              const int* __restrict__ dst,
                                              const int* __restrict__ inv,
                                              const int* __restrict__ sortid,
                                              const int* __restrict__ offs,
                                              int* __restrict__ cursor,
                                              int* __restrict__ col,
                                              const float* __restrict__ W,
                                              unsigned short* __restrict__ Whi,
                                              const float* __restrict__ x,
                                              const float* __restrict__ dinv,
                                              unsigned short* __restrict__ g) {
    int b = blockIdx.x;
    if (b < EE / 256) {
        int e = b * 256 + threadIdx.x;
        int pd = inv[dst[e]];
        int ps = inv[src[e]];
        int slot = atomicAdd(&cursor[pd], 1);
        col[offs[pd] + slot] = ps;
    } else if (b < EE / 256 + NL * 2048 / 256) {
        // fp32 W -> bf16 in MFMA B-fragment order:
        // [l][kstep(4)][ntile(8)][lane(64)][j(8)]; k=ks*32+(lane>>4)*8+j, n=nt*16+(lane&15)
        int t = (b - EE / 256) * 256 + threadIdx.x;
        int l = t >> 11;
        int rem = t & 2047;
        int ks = rem >> 9;
        int rem2 = rem & 511;
        int nt = rem2 >> 6;
        int L = rem2 & 63;
        const float* Wl = W + (size_t)l * FD * FD;
        int kbase = ks * 32 + ((L >> 4) << 3);
        int n = nt * 16 + (L & 15);
        v8s hv;
#pragma unroll
        for (int j = 0; j < 8; j++)
            hv[j] = (short)f2bf(Wl[(size_t)(kbase + j) * FD + n]);
        *(v8s*)(Whi + (size_t)t * 8) = hv;
    } else {
        // g0[p] = bf16(dinv_p[p] * x[sortid[p]])
        int i = (b - EE / 256 - NL * 2048 / 256) * 256 + threadIdx.x;
        int p = i >> 4;
        int ch = i & 15;
        int orig = sortid[p];
        float di = dinv[p];
        const float* xr = x + (size_t)orig * FD + ch * 8;
        float4 a = *(const float4*)xr;
        float4 c = *(const float4*)(xr + 4);
        v8s o;
        o[0] = (short)f2bf(di * a.x); o[1] = (short)f2bf(di * a.y);
        o[2] = (short)f2bf(di * a.z); o[3] = (short)f2bf(di * a.w);
        o[4] = (short)f2bf(di * c.x); o[5] = (short)f2bf(di * c.y);
        o[6] = (short)f2bf(di * c.z); o[7] = (short)f2bf(di * c.w);
        *(v8s*)(g + (size_t)p * FD + ch * 8) = o;
    }
}

// ---------- fused layer (permuted space) ----------
// Degree-sorted: block b owns 16 consecutive sorted nodes -> near-equal
// degree per wave/block -> max ~= mean (kills the straggler waste that
// R7's decomposition identified: E[max-of-16 Poisson(8)] ~ 2x mean).
__global__ __launch_bounds__(256, 8) void k_layer(
        const unsigned short* __restrict__ g,
        const int* __restrict__ offs,
        const int* __restrict__ col,
        const unsigned short* __restrict__ Whi,
        const float* __restrict__ dinv,
        const float* __restrict__ bias,
        unsigned short* __restrict__ gout,
        const int* __restrict__ sortid,
        const float* __restrict__ x,
        const float* __restrict__ cw,
        const float* __restrict__ cb,
        float* __restrict__ out,
        int last) {
    __shared__ unsigned short sA[MROW * SROW];
    __shared__ float sDinv[MROW];
    int tid = threadIdx.x;
    int lane = tid & 63;
    int w = tid >> 6;
    int row0 = blockIdx.x * MROW;
    int fg = lane >> 4;        // node subgroup 0..3 (one node per group)
    int fl = lane & 15;        // feature chunk (8 feats = 16B)
    const unsigned short* gf = g + fl * 8;

    if (tid < MROW) sDinv[tid] = dinv[row0 + tid];

    int nbase = row0 + w * 4;                      // multiple of 4 -> aligned
    int4 ov = *(const int4*)(offs + nbase);
    int o4 = offs[nbase + 4];
    int B0 = ov.x;
    int Etot = o4 - B0;

    if (Etot <= 64) {
        // fast path: one coalesced col window covers all 4 nodes
        int c = (lane < Etot) ? col[B0 + lane] : 0;
        int node = nbase + fg;
        int sg = ((fg == 0) ? ov.x : (fg == 1) ? ov.y : (fg == 2) ? ov.z : ov.w) - B0;
        int eg = ((fg == 0) ? ov.y : (fg == 1) ? ov.z : (fg == 2) ? ov.w : o4) - B0;
        int len = eg - sg;
        int m = max(len, __shfl_xor(len, 16));
        m = max(m, __shfl_xor(m, 32));      // max deg over the 4 groups (~equal now)
        float acc[8];
#pragma unroll
        for (int k = 0; k < 8; k++) acc[k] = 0.f;
        for (int j = 0; j < m; j += 6) {
            int i0 = sg + j,     i1 = sg + j + 1, i2 = sg + j + 2;
            int i3 = sg + j + 3, i4 = sg + j + 4, i5 = sg + j + 5;
            bool p0 = i0 < eg, p1 = i1 < eg, p2 = i2 < eg;
            bool p3 = i3 < eg, p4 = i4 < eg, p5 = i5 < eg;
            int s0 = __shfl(c, i0 & 63);
            int s1 = __shfl(c, i1 & 63);
            int s2 = __shfl(c, i2 & 63);
            int s3 = __shfl(c, i3 & 63);
            int s4 = __shfl(c, i4 & 63);
            int s5 = __shfl(c, i5 & 63);
            v8s r0, r1, r2, r3, r4, r5;
            if (p0) r0 = *(const v8s*)(gf + (size_t)s0 * FD);
            if (p1) r1 = *(const v8s*)(gf + (size_t)s1 * FD);
            if (p2) r2 = *(const v8s*)(gf + (size_t)s2 * FD);
            if (p3) r3 = *(const v8s*)(gf + (size_t)s3 * FD);
            if (p4) r4 = *(const v8s*)(gf + (size_t)s4 * FD);
            if (p5) r5 = *(const v8s*)(gf + (size_t)s5 * FD);
            if (p0) acc8_bf16(acc, r0);
            if (p1) acc8_bf16(acc, r1);
            if (p2) acc8_bf16(acc, r2);
            if (p3) acc8_bf16(acc, r3);
            if (p4) acc8_bf16(acc, r4);
            if (p5) acc8_bf16(acc, r5);
        }
        v8s selfv = *(const v8s*)(gf + (size_t)node * FD);
        acc8_bf16(acc, selfv);   // self loop
        float di = dinv[node];
        unsigned pk[4];
#pragma unroll
        for (int k = 0; k < 4; k++) {
            pk[k] = (unsigned)f2bf(di * acc[2 * k]) |
                    ((unsigned)f2bf(di * acc[2 * k + 1]) << 16);
        }
        *(v8s*)&sA[(w * 4 + fg) * SROW + fl * 8] = *(v8s*)pk;  // all lanes write
    } else {
        // rare path (degree tail, ~0.2% of nodes): per-node col loads
        for (int r = 0; r < 4; r++) {
            int nloc = w * 4 + r;
            int node = row0 + nloc;
            float acc[8];
#pragma unroll
            for (int k = 0; k < 8; k++) acc[k] = 0.f;
            int b = offs[node], e = offs[node + 1];
            int deg = e - b;
            for (int base = 0; base < deg; base += 64) {
                int n = min(deg - base, 64);
                int c = (lane < n) ? col[b + base + lane] : 0;
                for (int j = 0; j < n; j += 8) {
                    int e0 = j + fg, e1 = j + 4 + fg;
                    int s0 = __shfl(c, e0 & 63);
                    int s1 = __shfl(c, e1 & 63);
                    bool p0 = e0 < n, p1 = e1 < n;
                    v8s r0, r1;
                    if (p0) r0 = *(const v8s*)(gf + (size_t)s0 * FD);
                    if (p1) r1 = *(const v8s*)(gf + (size_t)s1 * FD);
                    if (p0) acc8_bf16(acc, r0);
                    if (p1) acc8_bf16(acc, r1);
                }
            }
#pragma unroll
            for (int k = 0; k < 8; k++) {
                acc[k] += __shfl_xor(acc[k], 16);
                acc[k] += __shfl_xor(acc[k], 32);
            }
            v8s sv = *(const v8s*)(gf + (size_t)node * FD);
            acc8_bf16(acc, sv);
            if (fg == 0) {
                float di = dinv[node];
                unsigned pk[4];
#pragma unroll
                for (int k = 0; k < 4; k++) {
                    pk[k] = (unsigned)f2bf(di * acc[2 * k]) |
                            ((unsigned)f2bf(di * acc[2 * k + 1]) << 16);
                }
                *(v8s*)&sA[nloc * SROW + fl * 8] = *(v8s*)pk;
            }
        }
    }
    __syncthreads();

    // phase 2: 16x128 @ 128x128 MFMA (A from LDS, W bf16 from L2)
    v4f a0 = (v4f){0.f, 0.f, 0.f, 0.f};
    v4f a1 = (v4f){0.f, 0.f, 0.f, 0.f};
#pragma unroll
    for (int ks = 0; ks < 4; ks++) {
        v8s ah = *(const v8s*)&sA[(lane & 15) * SROW + ks * 32 + ((lane >> 4) << 3)];
        size_t bo0 = ((size_t)(ks * 8 + w * 2) * 64 + lane) * 8;
        size_t bo1 = ((size_t)(ks * 8 + w * 2 + 1) * 64 + lane) * 8;
        v8s bh0 = *(const v8s*)(Whi + bo0);
        v8s bh1 = *(const v8s*)(Whi + bo1);
        a0 = __builtin_amdgcn_mfma_f32_16x16x32_bf16(ah, bh0, a0, 0, 0, 0);
        a1 = __builtin_amdgcn_mfma_f32_16x16x32_bf16(ah, bh1, a1, 0, 0, 0);
    }
    __syncthreads();  // before reusing sA

    // epilogue: bias + relu (+ dinv unless last), into sA
    float bb0 = bias[w * 32 + (lane & 15)];
    float bb1 = bias[w * 32 + 16 + (lane & 15)];
#pragma unroll
    for (int nt = 0; nt < 2; nt++) {
        int col_l = w * 32 + nt * 16 + (lane & 15);
        float bb = nt ? bb1 : bb0;
        v4f a = nt ? a1 : a0;
#pragma unroll
        for (int rg = 0; rg < 4; rg++) {
            int row_l = ((lane >> 4) << 2) + rg;
            float v = fmaxf(a[rg] + bb, 0.f);
            if (!last) v *= sDinv[row_l];
            sA[row_l * SROW + col_l] = f2bf(v);
        }
    }
    __syncthreads();

    if (!last) {
        // coalesced store of 16 permuted rows
        int orow = tid >> 4;
        int ocol = (tid & 15) * 8;
        *(v8s*)(gout + (size_t)(row0 + orow) * FD + ocol) =
            *(const v8s*)&sA[orow * SROW + ocol];
    } else {
        // fused classifier: out[orig] = (h + x[orig]) @ cw + cb, h in sA
        int row = tid >> 4;          // 0..15
        int t = tid & 15;            // feature octet
        int orig = sortid[row0 + row];
        const unsigned short* hr = &sA[row * SROW + t * 8];
        const float* xr = x + (size_t)orig * FD + t * 8;
        float xv[8];
        *(float4*)&xv[0] = *(const float4*)xr;
        *(float4*)&xv[4] = *(const float4*)(xr + 4);
        float p0 = 0.f, p1 = 0.f, p2 = 0.f, p3 = 0.f;
#pragma unroll
        for (int j = 0; j < 8; j++) {
            float s = bf2f(hr[j]) + xv[j];
            float4 wv = *(const float4*)(cw + (size_t)(t * 8 + j) * 4);
            p0 += s * wv.x; p1 += s * wv.y; p2 += s * wv.z; p3 += s * wv.w;
        }
#pragma unroll
        for (int off = 1; off < 16; off <<= 1) {
            p0 += __shfl_xor(p0, off);
            p1 += __shfl_xor(p1, off);
            p2 += __shfl_xor(p2, off);
            p3 += __shfl_xor(p3, off);
        }
        if (t == 0) {
            float4 r = make_float4(p0 + cb[0], p1 + cb[1], p2 + cb[2], p3 + cb[3]);
            *(float4*)(out + (size_t)orig * 4) = r;
        }
    }
}

extern "C" void kernel_launch(void* const* d_in, const int* in_sizes, int n_in,
                              void* d_out, int out_size, void* d_ws, size_t ws_size,
                              hipStream_t stream) {
    const float* x       = (const float*)d_in[0];
    const int* ei        = (const int*)d_in[1];       // [2][EE], int32
    const float* weights = (const float*)d_in[2];
    const float* biases  = (const float*)d_in[3];
    const float* cls_w   = (const float*)d_in[4];
    const float* cls_b   = (const float*)d_in[5];
    float* out = (float*)d_out;

    char* ws = (char*)d_ws;
    size_t off = 0;
    auto alloc = [&](size_t bytes) -> void* {
        off = (off + 255) & ~(size_t)255;
        void* p = ws + off;
        off += bytes;
        return p;
    };
    int*   cnt    = (int*)alloc((size_t)NN * 4);
    int*   cursor = (int*)alloc((size_t)NN * 4);
    float* dinv   = (float*)alloc((size_t)NN * 4);
    int*   offs   = (int*)alloc((size_t)(NN + 1) * 4);
    int*   bsum   = (int*)alloc((size_t)128 * 4);
    int*   boff   = (int*)alloc((size_t)128 * 4);
    int*   hist   = (int*)alloc((size_t)128 * 4);     // hist[64] + hcur[64]
    int*   hoff   = (int*)alloc((size_t)64 * 4);
    int*   sortid = (int*)alloc((size_t)NN * 4);
    int*   inv    = (int*)alloc((size_t)NN * 4);
    int*   cntS   = (int*)alloc((size_t)NN * 4);
    int*   col    = (int*)alloc((size_t)EE * 4);
    unsigned short* Whi = (unsigned short*)alloc((size_t)NL * FD * FD * 2);
    unsigned short* h0  = (unsigned short*)alloc((size_t)NN * FD * 2);
    unsigned short* h1  = (unsigned short*)alloc((size_t)NN * FD * 2);

    const int* srcv = ei;
    const int* dstv = ei + EE;

    hipMemsetAsync(cnt, 0, (size_t)NN * 4, stream);
    hipMemsetAsync(cursor, 0, (size_t)NN * 4, stream);
    hipMemsetAsync(hist, 0, (size_t)128 * 4, stream);
    k_deg<<<EE / 256, 256, 0, stream>>>(dstv, cnt);
    k_hist<<<NN / 256, 256, 0, stream>>>(cnt, hist);
    k_binscan<<<1, 64, 0, stream>>>(hist, hoff);
    k_scatter<<<NN / 256, 256, 0, stream>>>(cnt, hoff, hist + 64,
                                            sortid, inv, cntS);
    k_scanA<<<128, 256, 0, stream>>>(cntS, bsum);
    k_scanB<<<1, 128, 0, stream>>>(bsum, boff, offs);
    k_scanC<<<128, 256, 0, stream>>>(cntS, boff, offs, dinv);
    k_prep<<<EE / 256 + NL * 2048 / 256 + NN * FD / 2048, 256, 0, stream>>>(
        srcv, dstv, inv, sortid, offs, cursor, col,
        weights, Whi, x, dinv, h1);  // g0 in h1 (permuted)

    const unsigned short* gin = h1;
    for (int l = 0; l < NL; l++) {
        unsigned short* gout = (l & 1) ? h1 : h0;
        k_layer<<<NN / MROW, 256, 0, stream>>>(gin, offs, col,
                                               Whi + (size_t)l * FD * FD,
                                               dinv, biases + (size_t)l * FD,
                                               gout, sortid, x, cls_w, cls_b,
                                               out, l == NL - 1);
        gin = gout;
    }
}